// Round 1
// baseline (97.351 us; speedup 1.0000x reference)
//
#include <hip/hip_runtime.h>
#include <math.h>

// Problem constants (fixed by setup_inputs): B=4, N=8192, P=2048, NSAMPLE=32.
constexpr int Bc  = 4;
constexpr int Nc  = 8192;
constexpr int Pc  = 2048;
constexpr int Sc  = 32;
constexpr int CHc = 34;   // 2 invariance + 4*8 quat channels

// JAX >= 0.4.36 defaults jax_threefry_partitionable=True. If the harness's JAX
// uses the legacy counter layout, set this to 0 (round-2 fallback).
#define THREEFRY_PARTITIONABLE 1

#define FMUL __fmul_rn
#define FADD __fadd_rn
#define FSUB __fsub_rn

__device__ __forceinline__ unsigned tf_rotl(unsigned x, int r) {
  return (x << r) | (x >> (32 - r));
}

// Threefry-2x32, 20 rounds, key = (0, 42)  [jax.random.key(42)]
__device__ __forceinline__ void threefry2x32_k42(unsigned& x0, unsigned& x1) {
  const unsigned ks0 = 0u, ks1 = 42u, ks2 = 0u ^ 42u ^ 0x1BD11BDAu;
  x0 += ks0; x1 += ks1;
#define TF_ROUND(r) { x0 += x1; x1 = tf_rotl(x1, (r)); x1 ^= x0; }
  TF_ROUND(13) TF_ROUND(15) TF_ROUND(26) TF_ROUND(6)
  x0 += ks1; x1 += ks2 + 1u;
  TF_ROUND(17) TF_ROUND(29) TF_ROUND(16) TF_ROUND(24)
  x0 += ks2; x1 += ks0 + 2u;
  TF_ROUND(13) TF_ROUND(15) TF_ROUND(26) TF_ROUND(6)
  x0 += ks0; x1 += ks1 + 3u;
  TF_ROUND(17) TF_ROUND(29) TF_ROUND(16) TF_ROUND(24)
  x0 += ks1; x1 += ks2 + 4u;
  TF_ROUND(13) TF_ROUND(15) TF_ROUND(26) TF_ROUND(6)
  x0 += ks2; x1 += ks0 + 5u;
#undef TF_ROUND
}

// Bit-exact replica of (jax.random.uniform(key(42), (B,1,P,S)) - 0.5) * 2*pi
// at flat counter n. Total count = B*1*P*S = 262144.
__device__ __forceinline__ float jax_rnd_angle(unsigned n) {
#if THREEFRY_PARTITIONABLE
  unsigned x0 = 0u, x1 = n;          // hi32(n)=0, lo32(n)=n
  threefry2x32_k42(x0, x1);
  unsigned bits = x0 ^ x1;
#else
  const unsigned half = (unsigned)(Bc * Pc * Sc) / 2u;  // 131072
  unsigned x0, x1;
  bool second = (n >= half);
  if (second) { x0 = n - half; x1 = n; } else { x0 = n; x1 = n + half; }
  threefry2x32_k42(x0, x1);
  unsigned bits = second ? x1 : x0;
#endif
  // float in [0,1): bitcast((bits>>9)|0x3F800000) - 1.0
  float u = __uint_as_float((bits >> 9) | 0x3F800000u) - 1.0f;
  return FMUL(FSUB(u, 0.5f), (float)(2.0 * 3.141592653589793));
}

__device__ __forceinline__ float dot3rn(float ax, float ay, float az,
                                        float bx, float by, float bz) {
  // XLA reduce order over axis of size 3: ((x + y) + z)
  return FADD(FADD(FMUL(ax, bx), FMUL(ay, by)), FMUL(az, bz));
}

__global__ __launch_bounds__(256)
void qgq_kernel(const float* __restrict__ xyz,      // (B, N, 3)
                const float* __restrict__ new_xyz,  // (B, P, 3)
                float* __restrict__ out)            // (B, 34, P, 32)
{
  __shared__ int sIdx[4][Sc];

  const int wave = threadIdx.x >> 6;
  const int lane = threadIdx.x & 63;
  const int q    = blockIdx.x * 4 + wave;   // query id in [0, B*P)
  const int b    = q >> 11;                 // / 2048
  const int p    = q & 2047;

  const float* xb = xyz + (size_t)b * Nc * 3;
  const float cx = new_xyz[((size_t)b * Pc + p) * 3 + 0];
  const float cy = new_xyz[((size_t)b * Pc + p) * 3 + 1];
  const float cz = new_xyz[((size_t)b * Pc + p) * 3 + 2];

  // ---------------- Stage 1: ball query (first 32 in-ball indices, ascending)
  const float R2 = (float)(0.2 * 0.2);   // float32(RADIUS*RADIUS), exact JAX cast
  int cnt = 0;
  for (int base = 0; base < Nc; base += 64) {   // N % 64 == 0
    const int i = base + lane;
    const float x = xb[i * 3 + 0];
    const float y = xb[i * 3 + 1];
    const float z = xb[i * 3 + 2];
    const float dx = FSUB(cx, x);
    const float dy = FSUB(cy, y);
    const float dz = FSUB(cz, z);
    const float d2 = FADD(FADD(FMUL(dx, dx), FMUL(dy, dy)), FMUL(dz, dz));
    const bool m = d2 < R2;
    const unsigned long long mask = __ballot(m);
    if (m) {
      const int pos = cnt + (int)__popcll(mask & ((1ull << lane) - 1ull));
      if (pos < Sc) sIdx[wave][pos] = i;
    }
    cnt += (int)__popcll(mask);
    if (cnt >= Sc) break;
  }
  __syncthreads();   // sIdx visibility (all waves reach this)
  if (cnt > Sc) cnt = Sc;
  // cnt >= 1 always: the center point itself has d2 == 0.

  // ---------------- Stage 2: lanes 0..31 own slot j (upper half mirrors)
  const int j  = lane & 31;
  const int gi = sIdx[wave][(j < cnt) ? j : 0];   // pad with 'first'

  const float ptx = xb[gi * 3 + 0];
  const float pty = xb[gi * 3 + 1];
  const float ptz = xb[gi * 3 + 2];
  const float relx = FSUB(ptx, cx);
  const float rely = FSUB(pty, cy);
  const float relz = FSUB(ptz, cz);

  // p1 = normalize(center)  (single normalization; used for vert & sinus & inv)
  const float n1  = __fsqrt_rn(dot3rn(cx, cy, cz, cx, cy, cz));
  const float id1 = FADD(n1, 1e-6f);
  const float p1x = __fdiv_rn(cx, id1);
  const float p1y = __fdiv_rn(cy, id1);
  const float p1z = __fdiv_rn(cz, id1);

  // p2 = normalize(p1) (double normalization inside _project_one)
  const float n2  = __fsqrt_rn(dot3rn(p1x, p1y, p1z, p1x, p1y, p1z));
  const float id2 = FADD(n2, 1e-6f);
  const float p2x = __fdiv_rn(p1x, id2);
  const float p2y = __fdiv_rn(p1y, id2);
  const float p2z = __fdiv_rn(p1z, id2);

  const bool colin = fabsf(p2x) > (float)(1.0 - 0.001);
  const float rxv = colin ? FMUL(-p2y, p2x) : FSUB(1.0f, FMUL(p2x, p2x));
  const float ryv = colin ? FSUB(1.0f, FMUL(p2y, p2y)) : FMUL(-p2x, p2y);
  const float rzv = colin ? FMUL(-p2y, p2z) : FMUL(-p2x, p2z);
  const float nr  = __fsqrt_rn(dot3rn(rxv, ryv, rzv, rxv, ryv, rzv));
  const float idr = FADD(nr, 1e-6f);
  const float refx = __fdiv_rn(rxv, idr);
  const float refy = __fdiv_rn(ryv, idr);
  const float refz = __fdiv_rn(rzv, idr);

  // projs = normalize(rel - (p1.rel)*p1)
  const float sdot = dot3rn(p1x, p1y, p1z, relx, rely, relz);
  const float wx = FSUB(relx, FMUL(sdot, p1x));
  const float wy = FSUB(rely, FMUL(sdot, p1y));
  const float wz = FSUB(relz, FMUL(sdot, p1z));
  const float nw  = __fsqrt_rn(dot3rn(wx, wy, wz, wx, wy, wz));
  const float idw = FADD(nw, 1e-6f);
  const float prx = __fdiv_rn(wx, idw);
  const float pry = __fdiv_rn(wy, idw);
  const float prz = __fdiv_rn(wz, idw);

  const float s2 = dot3rn(prx, pry, prz, prx, pry, prz);

  float angle;
  if (s2 < 1e-12f) {
    const unsigned n = ((unsigned)q << 5) | (unsigned)j;  // flat idx in (B,1,P,S)
    angle = jax_rnd_angle(n);
  } else {
    // cross(ref, projs) . p1  and  ref . projs
    const float ccx = FSUB(FMUL(refy, prz), FMUL(refz, pry));
    const float ccy = FSUB(FMUL(refz, prx), FMUL(refx, prz));
    const float ccz = FSUB(FMUL(refx, pry), FMUL(refy, prx));
    const float sinus   = dot3rn(ccx, ccy, ccz, p1x, p1y, p1z);
    const float cosinus = dot3rn(refx, refy, refz, prx, pry, prz);
    angle = atan2f(sinus, cosinus);
  }

  // ---------------- Stable ascending sort of (angle, j) across lanes 0..31
  // Key: total-order float bits (matches XLA: -0 < +0, no NaNs here) || slot j.
  const unsigned ab   = __float_as_uint(angle);
  const unsigned skey = (ab & 0x80000000u) ? ~ab : (ab | 0x80000000u);
  unsigned long long key = ((unsigned long long)skey << 32) | (unsigned)j;

  #pragma unroll
  for (int k = 2; k <= 32; k <<= 1) {
    #pragma unroll
    for (int jj = k >> 1; jj > 0; jj >>= 1) {
      const unsigned long long other = __shfl_xor(key, jj);
      const bool up      = ((lane & k) == 0);
      const bool lower   = ((lane & jj) == 0);
      const bool takeMin = (lower == up);
      const unsigned long long mn = (key < other) ? key : other;
      const unsigned long long mx = (key < other) ? other : key;
      key = takeMin ? mn : mx;
    }
  }
  const int oj = (int)(key & 31u);   // original slot that lands at position `lane`

  // Gather sorted rel via shuffle (sources 0..31 are active)
  const float sx = __shfl(relx, oj);
  const float sy = __shfl(rely, oj);
  const float sz = __shfl(relz, oj);

  // ---------------- Outputs (2% tolerance: plain f32 math is fine here)
  const float dotr  = sx * sx + sy * sy + sz * sz;
  const float norm2 = sqrtf(dotr + 1e-12f);
  float cosang = (p1x * sx + p1y * sy + p1z * sz) / norm2;
  const float CL = (float)(1.0 - 1e-6);
  cosang = fminf(fmaxf(cosang, -CL), CL);
  const float ainv = acosf(cosang);

  const float dist = sqrtf(dotr);
  const float invd = 1.0f / (dist + 1e-6f);
  const float oxv = sx * invd, oyv = sy * invd, ozv = sz * invd;
  const float theta = (dist / 0.2f) * (float)(3.141592653589793 / 2.0);
  float st, ct;
  sincosf(theta, &st, &ct);
  const float qw = ct, qx = st * oxv, qy = st * oyv, qz = st * ozv;

  const size_t chs   = (size_t)Pc * Sc;
  const size_t baseo = (size_t)b * CHc * chs + (size_t)p * Sc + (size_t)j;

  if (lane < 32) {
    out[baseo + 0 * chs] = norm2;
    out[baseo + 1 * chs] = ainv;
  }
  // quats: channel = 2 + comp*8 + m ; value at pos s is q_comp[(s+m)%32]
  #pragma unroll
  for (int m = 0; m < 8; ++m) {
    const int src = (j + m) & 31;
    const float vw = __shfl(qw, src);
    const float vx = __shfl(qx, src);
    const float vy = __shfl(qy, src);
    const float vz = __shfl(qz, src);
    if (lane < 32) {
      out[baseo + (size_t)(2 + 0 * 8 + m) * chs] = vw;
      out[baseo + (size_t)(2 + 1 * 8 + m) * chs] = vx;
      out[baseo + (size_t)(2 + 2 * 8 + m) * chs] = vy;
      out[baseo + (size_t)(2 + 3 * 8 + m) * chs] = vz;
    }
  }
}

extern "C" void kernel_launch(void* const* d_in, const int* in_sizes, int n_in,
                              void* d_out, int out_size, void* d_ws, size_t ws_size,
                              hipStream_t stream) {
  const float* xyz     = (const float*)d_in[0];
  const float* new_xyz = (const float*)d_in[1];
  // d_in[2] (fps_idx) is dead: reference drops the fps column before use.
  float* out = (float*)d_out;

  const int nq = Bc * Pc;              // 8192 queries, 1 wave each
  dim3 grid(nq / 4), block(256);       // 4 waves per block
  hipLaunchKernelGGL(qgq_kernel, grid, block, 0, stream, xyz, new_xyz, out);
}

// Round 2
// 92.638 us; speedup vs baseline: 1.0509x; 1.0509x over previous
//
#include <hip/hip_runtime.h>
#include <math.h>

// Problem constants (fixed by setup_inputs): B=4, N=8192, P=2048, NSAMPLE=32.
constexpr int Bc  = 4;
constexpr int Nc  = 8192;
constexpr int Pc  = 2048;
constexpr int Sc  = 32;
constexpr int CHc = 34;   // 2 invariance + 4*8 quat channels

// JAX >= 0.4.36 defaults jax_threefry_partitionable=True (validated in R1).
#define THREEFRY_PARTITIONABLE 1

#define FMUL __fmul_rn
#define FADD __fadd_rn
#define FSUB __fsub_rn

__device__ __forceinline__ unsigned tf_rotl(unsigned x, int r) {
  return (x << r) | (x >> (32 - r));
}

// Threefry-2x32, 20 rounds, key = (0, 42)  [jax.random.key(42)]
__device__ __forceinline__ void threefry2x32_k42(unsigned& x0, unsigned& x1) {
  const unsigned ks0 = 0u, ks1 = 42u, ks2 = 0u ^ 42u ^ 0x1BD11BDAu;
  x0 += ks0; x1 += ks1;
#define TF_ROUND(r) { x0 += x1; x1 = tf_rotl(x1, (r)); x1 ^= x0; }
  TF_ROUND(13) TF_ROUND(15) TF_ROUND(26) TF_ROUND(6)
  x0 += ks1; x1 += ks2 + 1u;
  TF_ROUND(17) TF_ROUND(29) TF_ROUND(16) TF_ROUND(24)
  x0 += ks2; x1 += ks0 + 2u;
  TF_ROUND(13) TF_ROUND(15) TF_ROUND(26) TF_ROUND(6)
  x0 += ks0; x1 += ks1 + 3u;
  TF_ROUND(17) TF_ROUND(29) TF_ROUND(16) TF_ROUND(24)
  x0 += ks1; x1 += ks2 + 4u;
  TF_ROUND(13) TF_ROUND(15) TF_ROUND(26) TF_ROUND(6)
  x0 += ks2; x1 += ks0 + 5u;
#undef TF_ROUND
}

// Bit-exact replica of (jax.random.uniform(key(42), (B,1,P,S)) - 0.5) * 2*pi
// at flat counter n. Total count = B*1*P*S = 262144.
__device__ __forceinline__ float jax_rnd_angle(unsigned n) {
#if THREEFRY_PARTITIONABLE
  unsigned x0 = 0u, x1 = n;          // hi32(n)=0, lo32(n)=n
  threefry2x32_k42(x0, x1);
  unsigned bits = x0 ^ x1;
#else
  const unsigned half = (unsigned)(Bc * Pc * Sc) / 2u;  // 131072
  unsigned x0, x1;
  bool second = (n >= half);
  if (second) { x0 = n - half; x1 = n; } else { x0 = n; x1 = n + half; }
  threefry2x32_k42(x0, x1);
  unsigned bits = second ? x1 : x0;
#endif
  float u = __uint_as_float((bits >> 9) | 0x3F800000u) - 1.0f;
  return FMUL(FSUB(u, 0.5f), (float)(2.0 * 3.141592653589793));
}

__device__ __forceinline__ float dot3rn(float ax, float ay, float az,
                                        float bx, float by, float bz) {
  // XLA reduce order over axis of size 3: ((x + y) + z)
  return FADD(FADD(FMUL(ax, bx), FMUL(ay, by)), FMUL(az, bz));
}

// One block (256 threads) per query. Stage 1: block-wide ordered ball-query
// scan, 256 points/iter, first-32-by-index via ballot + LDS prefix.
// Stage 2: wave 0 computes angles, bitonic-sorts 32 keys, writes output.
__global__ __launch_bounds__(256)
void qgq_kernel(const float* __restrict__ xyz,      // (B, N, 3)
                const float* __restrict__ new_xyz,  // (B, P, 3)
                float* __restrict__ out)            // (B, 34, P, 32)
{
  __shared__ int sIdx[Sc];
  __shared__ unsigned long long smask[4];

  const int tid  = threadIdx.x;
  const int wave = tid >> 6;
  const int lane = tid & 63;
  const int q    = blockIdx.x;              // query id in [0, B*P)
  const int b    = q >> 11;                 // / 2048
  const int p    = q & 2047;

  const float* xb = xyz + (size_t)b * Nc * 3;
  const float cx = new_xyz[((size_t)b * Pc + p) * 3 + 0];
  const float cy = new_xyz[((size_t)b * Pc + p) * 3 + 1];
  const float cz = new_xyz[((size_t)b * Pc + p) * 3 + 2];

  // ---------------- Stage 1: first 32 in-ball indices, ascending -----------
  const float R2 = (float)(0.2 * 0.2);   // float32(RADIUS*RADIUS), exact JAX cast
  int before = 0;                         // block-uniform running count
  for (int base = 0; base < Nc; base += 256) {   // N % 256 == 0
    const int i = base + tid;
    const float x = xb[i * 3 + 0];
    const float y = xb[i * 3 + 1];
    const float z = xb[i * 3 + 2];
    const float dx = FSUB(cx, x);
    const float dy = FSUB(cy, y);
    const float dz = FSUB(cz, z);
    const float d2 = FADD(FADD(FMUL(dx, dx), FMUL(dy, dy)), FMUL(dz, dz));
    const bool m = d2 < R2;
    const unsigned long long mask = __ballot(m);
    if (lane == 0) smask[wave] = mask;
    __syncthreads();
    const int c0 = (int)__popcll(smask[0]);
    const int c1 = (int)__popcll(smask[1]);
    const int c2 = (int)__popcll(smask[2]);
    const int c3 = (int)__popcll(smask[3]);
    if (m) {
      int pos = before + (int)__popcll(mask & ((1ull << lane) - 1ull));
      if (wave > 0) pos += c0;
      if (wave > 1) pos += c1;
      if (wave > 2) pos += c2;
      if (pos < Sc) sIdx[pos] = i;
    }
    before += c0 + c1 + c2 + c3;          // identical in every thread
    if (before >= Sc) break;
    __syncthreads();                      // protect smask reuse next iter
  }
  __syncthreads();                        // sIdx visibility for wave 0
  int cnt = (before > Sc) ? Sc : before;
  // cnt >= 1 always: the center point itself has d2 == 0.

  if (wave != 0) return;                  // stage 2 runs on wave 0 only

  // ---------------- Stage 2: lanes 0..31 own slot j (upper half mirrors) ---
  const int j  = lane & 31;
  const int gi = sIdx[(j < cnt) ? j : 0];   // pad with 'first'

  const float ptx = xb[gi * 3 + 0];
  const float pty = xb[gi * 3 + 1];
  const float ptz = xb[gi * 3 + 2];
  const float relx = FSUB(ptx, cx);
  const float rely = FSUB(pty, cy);
  const float relz = FSUB(ptz, cz);

  // p1 = normalize(center)  (single normalization; used for vert & sinus & inv)
  const float n1  = __fsqrt_rn(dot3rn(cx, cy, cz, cx, cy, cz));
  const float id1 = FADD(n1, 1e-6f);
  const float p1x = __fdiv_rn(cx, id1);
  const float p1y = __fdiv_rn(cy, id1);
  const float p1z = __fdiv_rn(cz, id1);

  // p2 = normalize(p1) (double normalization inside _project_one)
  const float n2  = __fsqrt_rn(dot3rn(p1x, p1y, p1z, p1x, p1y, p1z));
  const float id2 = FADD(n2, 1e-6f);
  const float p2x = __fdiv_rn(p1x, id2);
  const float p2y = __fdiv_rn(p1y, id2);
  const float p2z = __fdiv_rn(p1z, id2);

  const bool colin = fabsf(p2x) > (float)(1.0 - 0.001);
  const float rxv = colin ? FMUL(-p2y, p2x) : FSUB(1.0f, FMUL(p2x, p2x));
  const float ryv = colin ? FSUB(1.0f, FMUL(p2y, p2y)) : FMUL(-p2x, p2y);
  const float rzv = colin ? FMUL(-p2y, p2z) : FMUL(-p2x, p2z);
  const float nr  = __fsqrt_rn(dot3rn(rxv, ryv, rzv, rxv, ryv, rzv));
  const float idr = FADD(nr, 1e-6f);
  const float refx = __fdiv_rn(rxv, idr);
  const float refy = __fdiv_rn(ryv, idr);
  const float refz = __fdiv_rn(rzv, idr);

  // projs = normalize(rel - (p1.rel)*p1)
  const float sdot = dot3rn(p1x, p1y, p1z, relx, rely, relz);
  const float wx = FSUB(relx, FMUL(sdot, p1x));
  const float wy = FSUB(rely, FMUL(sdot, p1y));
  const float wz = FSUB(relz, FMUL(sdot, p1z));
  const float nw  = __fsqrt_rn(dot3rn(wx, wy, wz, wx, wy, wz));
  const float idw = FADD(nw, 1e-6f);
  const float prx = __fdiv_rn(wx, idw);
  const float pry = __fdiv_rn(wy, idw);
  const float prz = __fdiv_rn(wz, idw);

  const float s2 = dot3rn(prx, pry, prz, prx, pry, prz);

  float angle;
  if (s2 < 1e-12f) {
    const unsigned n = ((unsigned)q << 5) | (unsigned)j;  // flat idx in (B,1,P,S)
    angle = jax_rnd_angle(n);
  } else {
    // cross(ref, projs) . p1  and  ref . projs
    const float ccx = FSUB(FMUL(refy, prz), FMUL(refz, pry));
    const float ccy = FSUB(FMUL(refz, prx), FMUL(refx, prz));
    const float ccz = FSUB(FMUL(refx, pry), FMUL(refy, prx));
    const float sinus   = dot3rn(ccx, ccy, ccz, p1x, p1y, p1z);
    const float cosinus = dot3rn(refx, refy, refz, prx, pry, prz);
    angle = atan2f(sinus, cosinus);
  }

  // ---------------- Stable ascending sort of (angle, j) across lanes 0..31
  const unsigned ab   = __float_as_uint(angle);
  const unsigned skey = (ab & 0x80000000u) ? ~ab : (ab | 0x80000000u);
  unsigned long long key = ((unsigned long long)skey << 32) | (unsigned)j;

  #pragma unroll
  for (int k = 2; k <= 32; k <<= 1) {
    #pragma unroll
    for (int jj = k >> 1; jj > 0; jj >>= 1) {
      const unsigned long long other = __shfl_xor(key, jj);
      const bool up      = ((lane & k) == 0);
      const bool lower   = ((lane & jj) == 0);
      const bool takeMin = (lower == up);
      const unsigned long long mn = (key < other) ? key : other;
      const unsigned long long mx = (key < other) ? other : key;
      key = takeMin ? mn : mx;
    }
  }
  const int oj = (int)(key & 31u);   // original slot that lands at position `lane`

  // Gather sorted rel via shuffle (sources 0..31 are active)
  const float sx = __shfl(relx, oj);
  const float sy = __shfl(rely, oj);
  const float sz = __shfl(relz, oj);

  // ---------------- Outputs (2% tolerance: plain f32 math is fine here)
  const float dotr  = sx * sx + sy * sy + sz * sz;
  const float norm2 = sqrtf(dotr + 1e-12f);
  float cosang = (p1x * sx + p1y * sy + p1z * sz) / norm2;
  const float CL = (float)(1.0 - 1e-6);
  cosang = fminf(fmaxf(cosang, -CL), CL);
  const float ainv = acosf(cosang);

  const float dist = sqrtf(dotr);
  const float invd = 1.0f / (dist + 1e-6f);
  const float oxv = sx * invd, oyv = sy * invd, ozv = sz * invd;
  const float theta = (dist / 0.2f) * (float)(3.141592653589793 / 2.0);
  float st, ct;
  sincosf(theta, &st, &ct);
  const float qw = ct, qx = st * oxv, qy = st * oyv, qz = st * ozv;

  const size_t chs   = (size_t)Pc * Sc;
  const size_t baseo = (size_t)b * CHc * chs + (size_t)p * Sc + (size_t)j;

  if (lane < 32) {
    out[baseo + 0 * chs] = norm2;
    out[baseo + 1 * chs] = ainv;
  }
  // quats: channel = 2 + comp*8 + m ; value at pos s is q_comp[(s+m)%32]
  #pragma unroll
  for (int m = 0; m < 8; ++m) {
    const int src = (j + m) & 31;
    const float vw = __shfl(qw, src);
    const float vx = __shfl(qx, src);
    const float vy = __shfl(qy, src);
    const float vz = __shfl(qz, src);
    if (lane < 32) {
      out[baseo + (size_t)(2 + 0 * 8 + m) * chs] = vw;
      out[baseo + (size_t)(2 + 1 * 8 + m) * chs] = vx;
      out[baseo + (size_t)(2 + 2 * 8 + m) * chs] = vy;
      out[baseo + (size_t)(2 + 3 * 8 + m) * chs] = vz;
    }
  }
}

extern "C" void kernel_launch(void* const* d_in, const int* in_sizes, int n_in,
                              void* d_out, int out_size, void* d_ws, size_t ws_size,
                              hipStream_t stream) {
  const float* xyz     = (const float*)d_in[0];
  const float* new_xyz = (const float*)d_in[1];
  // d_in[2] (fps_idx) is dead: reference drops the fps column before use.
  float* out = (float*)d_out;

  const int nq = Bc * Pc;              // 8192 queries, 1 block each
  dim3 grid(nq), block(256);
  hipLaunchKernelGGL(qgq_kernel, grid, block, 0, stream, xyz, new_xyz, out);
}

// Round 3
// 89.116 us; speedup vs baseline: 1.0924x; 1.0395x over previous
//
#include <hip/hip_runtime.h>
#include <math.h>

// Problem constants (fixed by setup_inputs): B=4, N=8192, P=2048, NSAMPLE=32.
constexpr int Bc  = 4;
constexpr int Nc  = 8192;
constexpr int Pc  = 2048;
constexpr int Sc  = 32;
constexpr int CHc = 34;   // 2 invariance + 4*8 quat channels

// JAX >= 0.4.36 defaults jax_threefry_partitionable=True (validated in R1).
#define THREEFRY_PARTITIONABLE 1

#define FMUL __fmul_rn
#define FADD __fadd_rn
#define FSUB __fsub_rn

__device__ __forceinline__ unsigned tf_rotl(unsigned x, int r) {
  return (x << r) | (x >> (32 - r));
}

// Threefry-2x32, 20 rounds, key = (0, 42)  [jax.random.key(42)]
__device__ __forceinline__ void threefry2x32_k42(unsigned& x0, unsigned& x1) {
  const unsigned ks0 = 0u, ks1 = 42u, ks2 = 0u ^ 42u ^ 0x1BD11BDAu;
  x0 += ks0; x1 += ks1;
#define TF_ROUND(r) { x0 += x1; x1 = tf_rotl(x1, (r)); x1 ^= x0; }
  TF_ROUND(13) TF_ROUND(15) TF_ROUND(26) TF_ROUND(6)
  x0 += ks1; x1 += ks2 + 1u;
  TF_ROUND(17) TF_ROUND(29) TF_ROUND(16) TF_ROUND(24)
  x0 += ks2; x1 += ks0 + 2u;
  TF_ROUND(13) TF_ROUND(15) TF_ROUND(26) TF_ROUND(6)
  x0 += ks0; x1 += ks1 + 3u;
  TF_ROUND(17) TF_ROUND(29) TF_ROUND(16) TF_ROUND(24)
  x0 += ks1; x1 += ks2 + 4u;
  TF_ROUND(13) TF_ROUND(15) TF_ROUND(26) TF_ROUND(6)
  x0 += ks2; x1 += ks0 + 5u;
#undef TF_ROUND
}

// Bit-exact replica of (jax.random.uniform(key(42), (B,1,P,S)) - 0.5) * 2*pi
// at flat counter n. Total count = B*1*P*S = 262144.
__device__ __forceinline__ float jax_rnd_angle(unsigned n) {
#if THREEFRY_PARTITIONABLE
  unsigned x0 = 0u, x1 = n;          // hi32(n)=0, lo32(n)=n
  threefry2x32_k42(x0, x1);
  unsigned bits = x0 ^ x1;
#else
  const unsigned half = (unsigned)(Bc * Pc * Sc) / 2u;  // 131072
  unsigned x0, x1;
  bool second = (n >= half);
  if (second) { x0 = n - half; x1 = n; } else { x0 = n; x1 = n + half; }
  threefry2x32_k42(x0, x1);
  unsigned bits = second ? x1 : x0;
#endif
  float u = __uint_as_float((bits >> 9) | 0x3F800000u) - 1.0f;
  return FMUL(FSUB(u, 0.5f), (float)(2.0 * 3.141592653589793));
}

__device__ __forceinline__ float dot3rn(float ax, float ay, float az,
                                        float bx, float by, float bz) {
  // XLA reduce order over axis of size 3: ((x + y) + z)
  return FADD(FADD(FMUL(ax, bx), FMUL(ay, by)), FMUL(az, bz));
}

// One block (256 threads) per query.
// Stage 1: ordered ball-query scan, 2048 points per tile (8 pts/thread, all
//   loads batched into one latency window), first-32-by-index via 8 wave
//   ballots + one LDS count exchange + ONE barrier per tile. Double-buffered
//   count array removes the trailing barrier. Avg ~1.25 tiles, max 4.
// Stage 2: wave 0 computes angles, bitonic-sorts 32 keys, writes output.
__global__ __launch_bounds__(256)
void qgq_kernel(const float* __restrict__ xyz,      // (B, N, 3)
                const float* __restrict__ new_xyz,  // (B, P, 3)
                float* __restrict__ out)            // (B, 34, P, 32)
{
  __shared__ int sIdx[Sc];
  __shared__ int sCnt[2][32];          // [tile parity][chunk c = k*4 + wave]

  const int tid  = threadIdx.x;
  const int wave = tid >> 6;
  const int lane = tid & 63;
  const int q    = blockIdx.x;              // query id in [0, B*P)
  const int b    = q >> 11;                 // / 2048
  const int p    = q & 2047;

  const float* xb = xyz + (size_t)b * Nc * 3;
  const float cx = new_xyz[((size_t)b * Pc + p) * 3 + 0];
  const float cy = new_xyz[((size_t)b * Pc + p) * 3 + 1];
  const float cz = new_xyz[((size_t)b * Pc + p) * 3 + 2];

  // ---------------- Stage 1: first 32 in-ball indices, ascending -----------
  const float R2 = (float)(0.2 * 0.2);   // float32(RADIUS*RADIUS), exact JAX cast
  int before = 0;                         // block-uniform running count
  #pragma unroll 1
  for (int tile = 0; tile < Nc / 2048; ++tile) {
    const int base = tile * 2048;
    const int par  = tile & 1;

    // Batch all 24 loads (independent -> single latency window).
    float xs[8], ys[8], zs[8];
    #pragma unroll
    for (int k = 0; k < 8; ++k) {
      const int i = base + k * 256 + tid;   // chunk c=k*4+wave covers 64 consec idx
      xs[k] = xb[i * 3 + 0];
      ys[k] = xb[i * 3 + 1];
      zs[k] = xb[i * 3 + 2];
    }

    unsigned long long msk[8];
    bool mm[8];
    #pragma unroll
    for (int k = 0; k < 8; ++k) {
      const float dx = FSUB(cx, xs[k]);
      const float dy = FSUB(cy, ys[k]);
      const float dz = FSUB(cz, zs[k]);
      const float d2 = FADD(FADD(FMUL(dx, dx), FMUL(dy, dy)), FMUL(dz, dz));
      mm[k]  = d2 < R2;
      msk[k] = __ballot(mm[k]);
    }

    if (lane == 0) {
      #pragma unroll
      for (int k = 0; k < 8; ++k)
        sCnt[par][k * 4 + wave] = (int)__popcll(msk[k]);
    }
    __syncthreads();

    // Per-thread redundant exclusive prefix over the 32 chunks (broadcast
    // LDS reads, conflict-free). Capture the prefix at this wave's 8 chunks.
    int run = before;
    int pfx[8];
    #pragma unroll
    for (int c = 0; c < 32; ++c) {
      if ((c & 3) == wave) pfx[c >> 2] = run;
      run += sCnt[par][c];
    }

    const unsigned long long below = (1ull << lane) - 1ull;
    #pragma unroll
    for (int k = 0; k < 8; ++k) {
      if (mm[k]) {
        const int pos = pfx[k] + (int)__popcll(msk[k] & below);
        if (pos < Sc) sIdx[pos] = base + k * 256 + tid;
      }
    }

    before = run;                       // identical in every thread
    if (before >= Sc) break;            // uniform; parity buffer makes next
                                        // tile's sCnt writes WAR-safe
  }
  __syncthreads();                      // sIdx visibility for wave 0
  int cnt = (before > Sc) ? Sc : before;
  // cnt >= 1 always: the center point itself has d2 == 0.

  if (wave != 0) return;                // stage 2 runs on wave 0 only

  // ---------------- Stage 2: lanes 0..31 own slot j (upper half mirrors) ---
  const int j  = lane & 31;
  const int gi = sIdx[(j < cnt) ? j : 0];   // pad with 'first'

  const float ptx = xb[gi * 3 + 0];
  const float pty = xb[gi * 3 + 1];
  const float ptz = xb[gi * 3 + 2];
  const float relx = FSUB(ptx, cx);
  const float rely = FSUB(pty, cy);
  const float relz = FSUB(ptz, cz);

  // p1 = normalize(center)  (single normalization; used for vert & sinus & inv)
  const float n1  = __fsqrt_rn(dot3rn(cx, cy, cz, cx, cy, cz));
  const float id1 = FADD(n1, 1e-6f);
  const float p1x = __fdiv_rn(cx, id1);
  const float p1y = __fdiv_rn(cy, id1);
  const float p1z = __fdiv_rn(cz, id1);

  // p2 = normalize(p1) (double normalization inside _project_one)
  const float n2  = __fsqrt_rn(dot3rn(p1x, p1y, p1z, p1x, p1y, p1z));
  const float id2 = FADD(n2, 1e-6f);
  const float p2x = __fdiv_rn(p1x, id2);
  const float p2y = __fdiv_rn(p1y, id2);
  const float p2z = __fdiv_rn(p1z, id2);

  const bool colin = fabsf(p2x) > (float)(1.0 - 0.001);
  const float rxv = colin ? FMUL(-p2y, p2x) : FSUB(1.0f, FMUL(p2x, p2x));
  const float ryv = colin ? FSUB(1.0f, FMUL(p2y, p2y)) : FMUL(-p2x, p2y);
  const float rzv = colin ? FMUL(-p2y, p2z) : FMUL(-p2x, p2z);
  const float nr  = __fsqrt_rn(dot3rn(rxv, ryv, rzv, rxv, ryv, rzv));
  const float idr = FADD(nr, 1e-6f);
  const float refx = __fdiv_rn(rxv, idr);
  const float refy = __fdiv_rn(ryv, idr);
  const float refz = __fdiv_rn(rzv, idr);

  // projs = normalize(rel - (p1.rel)*p1)
  const float sdot = dot3rn(p1x, p1y, p1z, relx, rely, relz);
  const float wx = FSUB(relx, FMUL(sdot, p1x));
  const float wy = FSUB(rely, FMUL(sdot, p1y));
  const float wz = FSUB(relz, FMUL(sdot, p1z));
  const float nw  = __fsqrt_rn(dot3rn(wx, wy, wz, wx, wy, wz));
  const float idw = FADD(nw, 1e-6f);
  const float prx = __fdiv_rn(wx, idw);
  const float pry = __fdiv_rn(wy, idw);
  const float prz = __fdiv_rn(wz, idw);

  const float s2 = dot3rn(prx, pry, prz, prx, pry, prz);

  float angle;
  if (s2 < 1e-12f) {
    const unsigned n = ((unsigned)q << 5) | (unsigned)j;  // flat idx in (B,1,P,S)
    angle = jax_rnd_angle(n);
  } else {
    // cross(ref, projs) . p1  and  ref . projs
    const float ccx = FSUB(FMUL(refy, prz), FMUL(refz, pry));
    const float ccy = FSUB(FMUL(refz, prx), FMUL(refx, prz));
    const float ccz = FSUB(FMUL(refx, pry), FMUL(refy, prx));
    const float sinus   = dot3rn(ccx, ccy, ccz, p1x, p1y, p1z);
    const float cosinus = dot3rn(refx, refy, refz, prx, pry, prz);
    angle = atan2f(sinus, cosinus);
  }

  // ---------------- Stable ascending sort of (angle, j) across lanes 0..31
  const unsigned ab   = __float_as_uint(angle);
  const unsigned skey = (ab & 0x80000000u) ? ~ab : (ab | 0x80000000u);
  unsigned long long key = ((unsigned long long)skey << 32) | (unsigned)j;

  #pragma unroll
  for (int k = 2; k <= 32; k <<= 1) {
    #pragma unroll
    for (int jj = k >> 1; jj > 0; jj >>= 1) {
      const unsigned long long other = __shfl_xor(key, jj);
      const bool up      = ((lane & k) == 0);
      const bool lower   = ((lane & jj) == 0);
      const bool takeMin = (lower == up);
      const unsigned long long mn = (key < other) ? key : other;
      const unsigned long long mx = (key < other) ? other : key;
      key = takeMin ? mn : mx;
    }
  }
  const int oj = (int)(key & 31u);   // original slot that lands at position `lane`

  // Gather sorted rel via shuffle (sources 0..31 are active)
  const float sx = __shfl(relx, oj);
  const float sy = __shfl(rely, oj);
  const float sz = __shfl(relz, oj);

  // ---------------- Outputs (2% tolerance: plain f32 math is fine here)
  const float dotr  = sx * sx + sy * sy + sz * sz;
  const float norm2 = sqrtf(dotr + 1e-12f);
  float cosang = (p1x * sx + p1y * sy + p1z * sz) / norm2;
  const float CL = (float)(1.0 - 1e-6);
  cosang = fminf(fmaxf(cosang, -CL), CL);
  const float ainv = acosf(cosang);

  const float dist = sqrtf(dotr);
  const float invd = 1.0f / (dist + 1e-6f);
  const float oxv = sx * invd, oyv = sy * invd, ozv = sz * invd;
  const float theta = (dist / 0.2f) * (float)(3.141592653589793 / 2.0);
  float st, ct;
  sincosf(theta, &st, &ct);
  const float qw = ct, qx = st * oxv, qy = st * oyv, qz = st * ozv;

  const size_t chs   = (size_t)Pc * Sc;
  const size_t baseo = (size_t)b * CHc * chs + (size_t)p * Sc + (size_t)j;

  if (lane < 32) {
    out[baseo + 0 * chs] = norm2;
    out[baseo + 1 * chs] = ainv;
  }
  // quats: channel = 2 + comp*8 + m ; value at pos s is q_comp[(s+m)%32]
  #pragma unroll
  for (int m = 0; m < 8; ++m) {
    const int src = (j + m) & 31;
    const float vw = __shfl(qw, src);
    const float vx = __shfl(qx, src);
    const float vy = __shfl(qy, src);
    const float vz = __shfl(qz, src);
    if (lane < 32) {
      out[baseo + (size_t)(2 + 0 * 8 + m) * chs] = vw;
      out[baseo + (size_t)(2 + 1 * 8 + m) * chs] = vx;
      out[baseo + (size_t)(2 + 2 * 8 + m) * chs] = vy;
      out[baseo + (size_t)(2 + 3 * 8 + m) * chs] = vz;
    }
  }
}

extern "C" void kernel_launch(void* const* d_in, const int* in_sizes, int n_in,
                              void* d_out, int out_size, void* d_ws, size_t ws_size,
                              hipStream_t stream) {
  const float* xyz     = (const float*)d_in[0];
  const float* new_xyz = (const float*)d_in[1];
  // d_in[2] (fps_idx) is dead: reference drops the fps column before use.
  float* out = (float*)d_out;

  const int nq = Bc * Pc;              // 8192 queries, 1 block each
  dim3 grid(nq), block(256);
  hipLaunchKernelGGL(qgq_kernel, grid, block, 0, stream, xyz, new_xyz, out);
}